// Round 1
// 137.764 us; speedup vs baseline: 1.0152x; 1.0152x over previous
//
#include <hip/hip_runtime.h>
#include <math.h>

#define SEQ 5
#define EMBC 64   // EMB == CLUSTER == 64

typedef float4 f4;

// ---- 16-lane subgroup reductions via DPP row_ror (VALU pipe, no LDS ops) ----
// row_ror:N ctrl = 0x120+N; rotation-reduce over 16 lanes == xor butterfly.
template<int CTRL>
__device__ __forceinline__ float dpp_rot(float v) {
    return __int_as_float(__builtin_amdgcn_update_dpp(
        0, __float_as_int(v), CTRL, 0xF, 0xF, true));
}
__device__ __forceinline__ float sub_sum(float v) {
    v += dpp_rot<0x128>(v);   // row_ror:8
    v += dpp_rot<0x124>(v);   // row_ror:4
    v += dpp_rot<0x122>(v);   // row_ror:2
    v += dpp_rot<0x121>(v);   // row_ror:1
    return v;
}
__device__ __forceinline__ float sub_max(float v) {
    v = fmaxf(v, dpp_rot<0x128>(v));
    v = fmaxf(v, dpp_rot<0x124>(v));
    v = fmaxf(v, dpp_rot<0x122>(v));
    v = fmaxf(v, dpp_rot<0x121>(v));
    return v;
}
__device__ __forceinline__ float dot4(f4 a, f4 b) {
    return fmaf(a.x, b.x, fmaf(a.y, b.y, fmaf(a.z, b.z, a.w * b.w)));
}
__device__ __forceinline__ f4 fma4(f4 a, float s, f4 c) {
    f4 r; r.x = fmaf(a.x, s, c.x); r.y = fmaf(a.y, s, c.y);
          r.z = fmaf(a.z, s, c.z); r.w = fmaf(a.w, s, c.w); return r;
}
// row softmax of a 64-float vector distributed as float4 over a 16-lane subgroup
__device__ __forceinline__ f4 sub_softmax(f4 a, float scale) {
    a.x *= scale; a.y *= scale; a.z *= scale; a.w *= scale;
    const float m = sub_max(fmaxf(fmaxf(a.x, a.y), fmaxf(a.z, a.w)));
    f4 e; e.x = __expf(a.x - m); e.y = __expf(a.y - m);
          e.z = __expf(a.z - m); e.w = __expf(a.w - m);
    const float inv = 1.0f / sub_sum(((e.x + e.y) + (e.z + e.w)));
    e.x *= inv; e.y *= inv; e.z *= inv; e.w *= inv;
    return e;
}

// ---- Fully fused kernel: w-softmax computed in-block, NO workspace use ----
__global__ __launch_bounds__(256) void rumc_fused(
    const int* __restrict__ u_idx, const int* __restrict__ X_idx,
    const int* __restrict__ y_idx,
    const float* __restrict__ item_emb, const float* __restrict__ user_emb,
    const float* __restrict__ ae_raw, const float* __restrict__ w_raw,
    float* __restrict__ out, int B)
{
    __shared__ f4 s_raw[EMBC * 16];  // w_raw[c][d] staged linear       (16 KB)
    __shared__ f4 s_w[EMBC * 17];    // wT[d][c4] PADDED: d*17 + c4     (17 KB)
                                     // pad row to 17 f4: producer write goes
                                     // 16-way conflict -> 4-way; consumer read
                                     // stays 2-way (free) + subgroup broadcast
    __shared__ f4 s_ae[16 * 16];     // softmaxed aey per subgroup       (4 KB)

    const int t = threadIdx.x;

    // stage w_raw -> LDS, coalesced (4 KB per wave-instruction)
    #pragma unroll
    for (int i = 0; i < 4; ++i)
        s_raw[t + 256 * i] = ((const f4*)w_raw)[t + 256 * i];

    const int wave = t >> 6;
    const int lane = t & 63;
    const int sub  = lane >> 4;    // subgroup 0..3
    const int sl   = lane & 15;    // lane within subgroup
    const int g    = wave * 4 + sub;

    int b = blockIdx.x * 16 + g;
    const bool live = (b < B);
    if (!live) b = B - 1;

    // ---- indices (independent of LDS; drained by barrier below) ----
    const int yi = y_idx[b];
    const int ui = u_idx[b];
    int xi[SEQ];
    #pragma unroll
    for (int s = 0; s < SEQ; ++s) xi[s] = X_idx[b * SEQ + s];

    __syncthreads();   // s_raw ready

    const f4* __restrict__ item4 = (const f4*)item_emb;
    const f4* __restrict__ user4 = (const f4*)user_emb;
    const f4* __restrict__ ae4   = (const f4*)ae_raw;

    // issue the ae gathers NOW: they fly during the w-softmax compute below
    f4 aey = ae4[yi * 16 + sl];
    f4 ax[SEQ];
    #pragma unroll
    for (int s = 0; s < SEQ; ++s) ax[s] = ae4[xi[s] * 16 + sl];

    // ---- in-block column softmax of w_raw*500 (axis=0) -> s_w[d][c4] ----
    // 4 threads per column d: thread (d,q) owns rows c = q*16 .. q*16+15.
    {
        const int d = t >> 2;          // 0..63
        const int q = t & 3;           // 0..3
        const float* __restrict__ sr = (const float*)s_raw;
        float x[16];
        #pragma unroll
        for (int k = 0; k < 16; ++k)
            x[k] = sr[(q * 16 + k) * EMBC + d] * 500.0f;   // 4-way bank alias, once
        float m = x[0];
        #pragma unroll
        for (int k = 1; k < 16; ++k) m = fmaxf(m, x[k]);
        m = fmaxf(m, __shfl_xor(m, 1, 64));   // combine the 4 q-partials
        m = fmaxf(m, __shfl_xor(m, 2, 64));
        float ssum = 0.0f;
        #pragma unroll
        for (int k = 0; k < 16; ++k) { x[k] = __expf(x[k] - m); ssum += x[k]; }
        ssum += __shfl_xor(ssum, 1, 64);
        ssum += __shfl_xor(ssum, 2, 64);
        const float inv = 1.0f / ssum;
        #pragma unroll
        for (int i = 0; i < 4; ++i) {
            f4 wv;
            wv.x = x[4 * i + 0] * inv; wv.y = x[4 * i + 1] * inv;
            wv.z = x[4 * i + 2] * inv; wv.w = x[4 * i + 3] * inv;
            s_w[d * 17 + q * 4 + i] = wv;     // wT[d][c], padded row
        }
    }

    __syncthreads();   // s_w ready; ae gathers drained too

    // ---- remaining gathers: latency covered by aey-softmax + v-loop ----
    f4 ye = item4[yi * 16 + sl];
    f4 xe[SEQ];
    #pragma unroll
    for (int s = 0; s < SEQ; ++s) xe[s] = item4[xi[s] * 16 + sl];
    f4 ue = user4[ui * 16 + sl];

    // ---- aey softmax, broadcast via subgroup-private LDS line ----
    aey = sub_softmax(aey, 50.0f);
    s_ae[g * 16 + sl] = aey;       // same-wave RAW: lgkmcnt-ordered, no barrier

    // ---- v[c] = sum_d w[c][d]*aey[d]; lane sl holds c = 4sl..4sl+3 ----
    f4 v; v.x = v.y = v.z = v.w = 0.0f;
    #pragma unroll
    for (int dd = 0; dd < 16; ++dd) {
        const f4 a  = s_ae[g * 16 + dd];              // 16-lane broadcast read
        const f4 w0 = s_w[(4 * dd + 0) * 17 + sl];
        const f4 w1 = s_w[(4 * dd + 1) * 17 + sl];
        const f4 w2 = s_w[(4 * dd + 2) * 17 + sl];
        const f4 w3 = s_w[(4 * dd + 3) * 17 + sl];
        v = fma4(w0, a.x, v);
        v = fma4(w1, a.y, v);
        v = fma4(w2, a.z, v);
        v = fma4(w3, a.w, v);
    }

    // padding_idx = 0 -> zero embedding row (ae row 0 is NOT zeroed)
    if (yi == 0) { ye.x = ye.y = ye.z = ye.w = 0.0f; }
    #pragma unroll
    for (int s = 0; s < SEQ; ++s)
        if (xi[s] == 0) { xe[s].x = xe[s].y = xe[s].z = xe[s].w = 0.0f; }

    // ---- per-position scores ----
    float sc[SEQ];
    #pragma unroll
    for (int s = 0; s < SEQ; ++s) {
        const f4 a = sub_softmax(ax[s], 50.0f);
        const float fac = sub_sum(dot4(a, v));      // aeX . (w @ aeY)
        const float dot = sub_sum(dot4(xe[s], ye)); // X_emb . y_emb
        const float tf = 1.0f - (float)(SEQ - 1 - s) * 0.1f;
        sc[s] = dot * __expf(fac) * tf;             // BETA == 1
    }

    // ---- softmax over SEQ (identical within subgroup) ----
    float ms = sc[0];
    #pragma unroll
    for (int s = 1; s < SEQ; ++s) ms = fmaxf(ms, sc[s]);
    float Z = 0.0f;
    #pragma unroll
    for (int s = 0; s < SEQ; ++s) { sc[s] = __expf(sc[s] - ms); Z += sc[s]; }
    const float invZ = 1.0f / Z;

    // ---- p = sum_s z_s*X_emb[s];  out = sigmoid((p*0.2 + u_emb) . y_emb) ----
    f4 p; p.x = p.y = p.z = p.w = 0.0f;
    #pragma unroll
    for (int s = 0; s < SEQ; ++s) p = fma4(xe[s], sc[s] * invZ, p);
    const f4 pu = fma4(p, 0.2f, ue);
    const float fin = sub_sum(dot4(pu, ye));
    if (live && sl == 0)
        out[b] = 1.0f / (1.0f + __expf(-fin));
}

extern "C" void kernel_launch(void* const* d_in, const int* in_sizes, int n_in,
                              void* d_out, int out_size, void* d_ws, size_t ws_size,
                              hipStream_t stream) {
    const int*   u        = (const int*)d_in[0];
    const int*   X        = (const int*)d_in[1];
    const int*   y        = (const int*)d_in[2];
    const float* item_emb = (const float*)d_in[3];
    const float* user_emb = (const float*)d_in[4];
    const float* ae_raw   = (const float*)d_in[5];
    const float* w_raw    = (const float*)d_in[6];
    float*       out      = (float*)d_out;
    (void)d_ws; (void)ws_size;   // workspace intentionally unused

    const int B = in_sizes[0];
    const int grid = (B + 15) / 16;

    rumc_fused<<<grid, 256, 0, stream>>>(u, X, y, item_emb, user_emb,
                                         ae_raw, w_raw, out, B);
}